// Round 8
// baseline (772.143 us; speedup 1.0000x reference)
//
#include <hip/hip_runtime.h>

typedef unsigned short ushort_t;
typedef unsigned int uint_t;
typedef __attribute__((ext_vector_type(8))) short short8;
typedef __attribute__((ext_vector_type(4))) float f32x4;

#define NN 500000
#define NE 1500000
#define BATCH 64
#define LSEQ 512
#define NSEG (BATCH * LSEQ)          // 32768
#define NBLK_E ((NN + 1023) / 1024)  // 489
#define NBLK_S (NSEG / 1024)         // 32

__device__ inline float bf2f(ushort_t u) {
    union { uint_t u; float f; } c; c.u = ((uint_t)u) << 16; return c.f;
}
__device__ inline ushort_t f2bf(float f) {
    union { float f; uint_t u; } c; c.f = f;
    uint_t u = c.u;
    return (ushort_t)((u + 0x7fff + ((u >> 16) & 1)) >> 16);  // RNE
}
__device__ inline int imax(int a, int b) { return a > b ? a : b; }

// ---------------- zero a 4B-word region ----------------
__global__ void k_zero(float* __restrict__ p, int n) {
    int i = blockIdx.x * blockDim.x + threadIdx.x;
    int stride = gridDim.x * blockDim.x;
    for (; i < n; i += stride) p[i] = 0.0f;
}

// ---------------- fused: dst histogram + node seg id/histogram ----------------
__global__ void k_hist2(const int* __restrict__ dst, const int* __restrict__ batch,
                        const int* __restrict__ depth, int* __restrict__ cnt,
                        int* __restrict__ segn, int* __restrict__ cnt2) {
    int t = blockIdx.x * blockDim.x + threadIdx.x;
    if (t < NE) {
        atomicAdd(&cnt[dst[t]], 1);
        if (t < NN) {
            int s = batch[t] * LSEQ + depth[t];
            segn[t] = s;
            atomicAdd(&cnt2[s], 1);
        }
    }
}

// ---------------- fused: dinv = rsqrt(deg+1) + W2 -> bf16 ----------------
__global__ void k_prep(const int* __restrict__ cnt, float* __restrict__ dinv,
                       const float* __restrict__ W2, ushort_t* __restrict__ W2b) {
    int i = blockIdx.x * blockDim.x + threadIdx.x;
    if (i < NN) dinv[i] = rsqrtf((float)cnt[i] + 1.0f);
    if (i < 64 * 64) W2b[i] = f2bf(W2[i]);
}

// ---------------- fused scans (edge-CSR over NN + node-sort over NSEG) ----------------
__device__ void scan_block_dev(const int* __restrict__ cnt, int* __restrict__ bsum,
                               int n, int blk, int* sd) {
    int tid = threadIdx.x;
    int base = blk * 1024 + tid * 4;
    int s = 0;
#pragma unroll
    for (int k = 0; k < 4; ++k) { int i = base + k; if (i < n) s += cnt[i]; }
    sd[tid] = s;
    __syncthreads();
    for (int off = 128; off; off >>= 1) {
        if (tid < off) sd[tid] += sd[tid + off];
        __syncthreads();
    }
    if (tid == 0) bsum[blk] = sd[0];
}

__global__ __launch_bounds__(256) void k_scan_block_f(const int* __restrict__ cnt, int* __restrict__ bsum,
                                                      const int* __restrict__ cnt2, int* __restrict__ bsum2) {
    __shared__ int sd[256];
    int blk = blockIdx.x;
    if (blk < NBLK_E) scan_block_dev(cnt, bsum, NN, blk, sd);
    else              scan_block_dev(cnt2, bsum2, NSEG, blk - NBLK_E, sd);
}

__device__ void scan_top_dev(int* __restrict__ b, int nblk, int* sd) {
    int tid = threadIdx.x;
    __syncthreads();
    int v = (tid < nblk) ? b[tid] : 0;
    sd[tid] = v;
    __syncthreads();
    for (int off = 1; off < 512; off <<= 1) {
        int t = (tid >= off) ? sd[tid - off] : 0;
        __syncthreads();
        sd[tid] += t;
        __syncthreads();
    }
    if (tid < nblk) b[tid] = sd[tid] - v;  // exclusive
}

__global__ __launch_bounds__(512) void k_scan_top_f(int* __restrict__ bsum, int* __restrict__ bsum2) {
    __shared__ int sd[512];
    scan_top_dev(bsum, NBLK_E, sd);
    scan_top_dev(bsum2, NBLK_S, sd);
}

__device__ void scan_final_dev(const int* __restrict__ cnt, const int* __restrict__ bsum,
                               int* __restrict__ rowoff, int* __restrict__ cursor,
                               int n, int total, int blk, int* sd) {
    int tid = threadIdx.x;
    int base = blk * 1024 + tid * 4;
    int loc[4]; int s = 0;
#pragma unroll
    for (int k = 0; k < 4; ++k) { int i = base + k; int c = (i < n) ? cnt[i] : 0; loc[k] = s; s += c; }
    sd[tid] = s;
    __syncthreads();
    for (int off = 1; off < 256; off <<= 1) {
        int t = (tid >= off) ? sd[tid - off] : 0;
        __syncthreads();
        sd[tid] += t;
        __syncthreads();
    }
    int texc = sd[tid] - s + bsum[blk];
#pragma unroll
    for (int k = 0; k < 4; ++k) {
        int i = base + k;
        if (i < n) { int v = texc + loc[k]; rowoff[i] = v; cursor[i] = v; }
    }
    if (blk == 0 && tid == 0) rowoff[n] = total;
}

__global__ __launch_bounds__(256) void k_scan_final_f(const int* __restrict__ cnt, const int* __restrict__ bsum,
                                                      int* __restrict__ rowoff, int* __restrict__ cursor,
                                                      const int* __restrict__ cnt2, const int* __restrict__ bsum2,
                                                      int* __restrict__ soff, int* __restrict__ cursor2) {
    __shared__ int sd[256];
    int blk = blockIdx.x;
    if (blk < NBLK_E) scan_final_dev(cnt, bsum, rowoff, cursor, NN, NE, blk, sd);
    else              scan_final_dev(cnt2, bsum2, soff, cursor2, NSEG, NN, blk - NBLK_E, sd);
}

// ------- fused reorder: edges into dst-CSR (src only, 4B) + nodes by seg -------
__global__ void k_reorder(const int* __restrict__ src, const int* __restrict__ dst,
                          const int* __restrict__ segn,
                          int* __restrict__ cursor, int* __restrict__ esrc,
                          int* __restrict__ cursor2, int* __restrict__ nord) {
    int e = blockIdx.x * blockDim.x + threadIdx.x;
    if (e < NE) {
        int d = dst[e];
        int pos = atomicAdd(&cursor[d], 1);
        esrc[pos] = src[e];
        if (e < NN) {
            int pos2 = atomicAdd(&cursor2[segn[e]], 1);
            nord[pos2] = e;
        }
    }
}

// ------- layer-1: CSR x-aggregation (exact f32) + dense build, 4-node interleave -------
// h1 = relu( W1^T (dv^2 x[n] + sum w x[src]) + b1 ), bf16; w = dinv[s]*dinv[n]
__global__ void k_build1(const float* __restrict__ x, const float* __restrict__ W1,
                         const float* __restrict__ b1, const float* __restrict__ dinv,
                         const int* __restrict__ rowoff, const int* __restrict__ esrc,
                         ushort_t* __restrict__ h1) {
    int lane = threadIdx.x & 63;
    int wave = (blockIdx.x * blockDim.x + threadIdx.x) >> 6;
    int nwaves = (gridDim.x * blockDim.x) >> 6;
    const float2* x2 = (const float2*)x;
    float w0 = W1[lane], w1 = W1[64 + lane], bj = b1[lane];
    for (int n0 = wave * 4; n0 < NN; n0 += nwaves * 4) {   // NN % 4 == 0
        float a0[4], a1[4], dvv[4]; int r[4], l[4];
#pragma unroll
        for (int j = 0; j < 4; ++j) {
            int n = n0 + j;
            dvv[j] = dinv[n];
            float2 xv = x2[n];
            a0[j] = dvv[j] * dvv[j] * xv.x;
            a1[j] = dvv[j] * dvv[j] * xv.y;
            r[j] = rowoff[n];
        }
#pragma unroll
        for (int j = 0; j < 4; ++j) l[j] = rowoff[n0 + j + 1] - r[j];
        int len = imax(imax(l[0], l[1]), imax(l[2], l[3]));
        for (int k = 0; k < len; ++k) {
#pragma unroll
            for (int j = 0; j < 4; ++j) {
                if (k < l[j]) {
                    int s = esrc[r[j] + k];
                    float w = dinv[s] * dvv[j];
                    float2 xv = x2[s];
                    a0[j] += w * xv.x;
                    a1[j] += w * xv.y;
                }
            }
        }
#pragma unroll
        for (int j = 0; j < 4; ++j)
            h1[(size_t)(n0 + j) * 64 + lane] = f2bf(fmaxf(a0[j] * w0 + a1[j] * w1 + bj, 0.0f));
    }
}

// ------- layer 2 GEMM via MFMA: xw2 = h1 @ W2  (M=NN, K=64, N=64, bf16) -------
__global__ __launch_bounds__(256) void k_gemm2(const ushort_t* __restrict__ h1,
                                               const ushort_t* __restrict__ W2b,
                                               ushort_t* __restrict__ xw2) {
    int lane = threadIdx.x & 63;
    int wave = (blockIdx.x * blockDim.x + threadIdx.x) >> 6;
    int nwaves = (gridDim.x * blockDim.x) >> 6;
    int col = lane & 15, kg = lane >> 4;

    short8 bfrag[2][4];
#pragma unroll
    for (int t = 0; t < 2; ++t)
#pragma unroll
        for (int j = 0; j < 4; ++j)
#pragma unroll
            for (int b = 0; b < 8; ++b) {
                int k = t * 32 + kg * 8 + b;
                bfrag[t][j][b] = (short)W2b[k * 64 + j * 16 + col];
            }

    const int NT = NN / 16;  // 31250
    for (int tile = wave; tile < NT; tile += nwaves) {
        size_t base = (size_t)tile * 16 * 64;
        short8 a0 = *(const short8*)(h1 + base + (size_t)col * 64 + kg * 8);
        short8 a1 = *(const short8*)(h1 + base + (size_t)col * 64 + 32 + kg * 8);
        f32x4 acc[4];
#pragma unroll
        for (int j = 0; j < 4; ++j) {
            acc[j] = (f32x4){0.0f, 0.0f, 0.0f, 0.0f};
            acc[j] = __builtin_amdgcn_mfma_f32_16x16x32_bf16(a0, bfrag[0][j], acc[j], 0, 0, 0);
            acc[j] = __builtin_amdgcn_mfma_f32_16x16x32_bf16(a1, bfrag[1][j], acc[j], 0, 0, 0);
        }
#pragma unroll
        for (int j = 0; j < 4; ++j)
#pragma unroll
            for (int r = 0; r < 4; ++r)
                xw2[base + (size_t)(kg * 4 + r) * 64 + j * 16 + col] = f2bf(acc[j][r]);
    }
}

// ------- layer-2 aggregate: node-parallel, 8-way interleave, rows out in seg order -------
// aggs[i] = relu( dv^2*xw2[nord[i]] + b2 + sum_e w*xw2[src] ),  bf16
__global__ __launch_bounds__(256) void k_agg(const ushort_t* __restrict__ xw2,
                                             const float* __restrict__ b2,
                                             const float* __restrict__ dinv,
                                             const int* __restrict__ rowoff,
                                             const int* __restrict__ esrc,
                                             const int* __restrict__ nord,
                                             ushort_t* __restrict__ aggs) {
    int lane = threadIdx.x & 63;
    int wave = (blockIdx.x * blockDim.x + threadIdx.x) >> 6;
    int nwaves = (gridDim.x * blockDim.x) >> 6;
    float bj = b2[lane];
    for (int i0 = wave * 8; i0 < NN; i0 += nwaves * 8) {   // NN % 8 == 0
        int n[8]; float dv8[8], a[8]; int r[8], l[8];
#pragma unroll
        for (int j = 0; j < 8; ++j) n[j] = nord[i0 + j];
#pragma unroll
        for (int j = 0; j < 8; ++j) { r[j] = rowoff[n[j]]; l[j] = rowoff[n[j] + 1] - r[j]; }
#pragma unroll
        for (int j = 0; j < 8; ++j) dv8[j] = dinv[n[j]];
#pragma unroll
        for (int j = 0; j < 8; ++j)
            a[j] = dv8[j] * dv8[j] * bf2f(xw2[(size_t)n[j] * 64 + lane]) + bj;
        int len = 0;
#pragma unroll
        for (int j = 0; j < 8; ++j) len = imax(len, l[j]);
        for (int k = 0; k < len; ++k) {
#pragma unroll
            for (int j = 0; j < 8; ++j) {
                if (k < l[j]) {
                    int s = esrc[r[j] + k];
                    a[j] += dinv[s] * dv8[j] * bf2f(xw2[(size_t)s * 64 + lane]);
                }
            }
        }
#pragma unroll
        for (int j = 0; j < 8; ++j)
            aggs[(size_t)(i0 + j) * 64 + lane] = f2bf(fmaxf(a[j], 0.0f));
    }
}

// ------- pool: wave per seg, sequential reads of sorted agg rows -------
__global__ __launch_bounds__(256) void k_pool2(const ushort_t* __restrict__ aggs,
                                               const int* __restrict__ soff,
                                               float* __restrict__ sumb,
                                               float* __restrict__ mxb,
                                               float* __restrict__ cntb) {
    int lane = threadIdx.x & 63;
    int seg = (blockIdx.x * blockDim.x + threadIdx.x) >> 6;
    if (seg >= NSEG) return;
    int i0 = soff[seg], i1 = soff[seg + 1];
    float ss = 0.0f, sm = 0.0f;
    for (int i = i0; i < i1; ++i) {
        float v = bf2f(aggs[(size_t)i * 64 + lane]);
        ss += v;
        sm = fmaxf(sm, v);
    }
    sumb[seg * 64 + lane] = ss;
    mxb[seg * 64 + lane] = sm;   // 0 for empty seg: matches where(cnt>0, mx, 0)
    if (lane == 0) cntb[seg] = (float)(i1 - i0);
}

// ---------------- conv1d(k=3,pad=1) + relu + partial mean over L ----------------
__global__ __launch_bounds__(256) void k_conv(const float* __restrict__ sum,
                                              const float* __restrict__ mxf,
                                              const float* __restrict__ cnt,
                                              const float* __restrict__ cw,
                                              const float* __restrict__ cb,
                                              float* __restrict__ pooled) {
    __shared__ float s_seq[66 * 129];
    int b = blockIdx.x >> 3;
    int l0 = (blockIdx.x & 7) * 64;
    int tid = threadIdx.x;
    for (int idx = tid; idx < 66 * 128; idx += 256) {
        int r = idx >> 7, i = idx & 127;
        int l = l0 + r - 1;
        float v = 0.0f;
        if (l >= 0 && l < LSEQ) {
            int seg = b * LSEQ + l;
            if (i < 64) v = sum[seg * 64 + i] / fmaxf(cnt[seg], 1.0f);
            else        v = mxf[seg * 64 + (i - 64)];
        }
        s_seq[r * 129 + i] = v;
    }
    __syncthreads();
    int l_local = tid & 63;
    int wid = tid >> 6;
    for (int rep = 0; rep < 16; ++rep) {
        int c = __builtin_amdgcn_readfirstlane(wid + 4 * rep);
        const float* wc = cw + c * 384;
        float acc = cb[c];
#pragma unroll
        for (int kk = 0; kk < 3; ++kk) {
            const float* sr = s_seq + (l_local + kk) * 129;
#pragma unroll 8
            for (int i = 0; i < 128; ++i)
                acc += sr[i] * wc[i * 3 + kk];
        }
        float y = fmaxf(acc, 0.0f);
#pragma unroll
        for (int off = 32; off; off >>= 1) y += __shfl_xor(y, off, 64);
        if (l_local == 0) atomicAdd(&pooled[b * 64 + c], y);
    }
}

// ---------------- head ----------------
__global__ void k_head(const float* __restrict__ pooled, const float* __restrict__ f1w,
                       const float* __restrict__ f1b, const float* __restrict__ f2w,
                       const float* __restrict__ f2b, float* __restrict__ out) {
    int b = blockIdx.x;
    int j = threadIdx.x;
    const float invL = 1.0f / (float)LSEQ;
    float z = f1b[j];
    for (int c = 0; c < 64; ++c)
        z += (pooled[b * 64 + c] * invL) * f1w[c * 64 + j];
    z = fmaxf(z, 0.0f);
    float v = z * f2w[j];
#pragma unroll
    for (int off = 32; off; off >>= 1) v += __shfl_xor(v, off, 64);
    if (j == 0) out[b] = 1.0f / (1.0f + expf(-(v + f2b[0])));
}

extern "C" void kernel_launch(void* const* d_in, const int* in_sizes, int n_in,
                              void* d_out, int out_size, void* d_ws, size_t ws_size,
                              hipStream_t stream) {
    const float* x     = (const float*)d_in[0];
    const int*   ei    = (const int*)d_in[1];
    const int*   depth = (const int*)d_in[2];
    const int*   batch = (const int*)d_in[3];
    const float* W1    = (const float*)d_in[4];
    const float* b1    = (const float*)d_in[5];
    const float* W2    = (const float*)d_in[6];
    const float* b2    = (const float*)d_in[7];
    const float* cw    = (const float*)d_in[8];
    const float* cb    = (const float*)d_in[9];
    const float* f1w   = (const float*)d_in[10];
    const float* f1b   = (const float*)d_in[11];
    const float* f2w   = (const float*)d_in[12];
    const float* f2b   = (const float*)d_in[13];
    float* out = (float*)d_out;

    // ---- workspace layout (~163 MB), each chunk 16B-aligned ----
    char* p = (char*)d_ws;
    auto bump = [&p](size_t bytes) { char* r = p; p += (bytes + 15) & ~(size_t)15; return r; };
    int*      cnt    = (int*)bump((size_t)NN * 4);          // zeroed ┐
    int*      cnt2   = (int*)bump((size_t)NSEG * 4);        //        │ one k_zero
    float*    pool   = (float*)bump((size_t)BATCH * 64 * 4);// zeroed ┘
    int*      rowoff = (int*)bump((size_t)(NN + 8) * 4);
    int*      cursor = (int*)bump((size_t)NN * 4);
    float*    dinv   = (float*)bump((size_t)NN * 4);
    int*      segn   = (int*)bump((size_t)NN * 4);
    int*      nord   = (int*)bump((size_t)NN * 4);
    int*      soff   = (int*)bump((size_t)(NSEG + 8) * 4);
    int*      cursor2= (int*)bump((size_t)NSEG * 4);
    int*      esrc   = (int*)bump((size_t)NE * 4);
    ushort_t* h1     = (ushort_t*)bump((size_t)NN * 128);   // reused as aggs after gemm2
    ushort_t* xw2    = (ushort_t*)bump((size_t)NN * 128);
    float*    sumb   = (float*)bump((size_t)NSEG * 64 * 4);
    float*    mxb    = (float*)bump((size_t)NSEG * 64 * 4);
    float*    cntb   = (float*)bump((size_t)NSEG * 4);
    ushort_t* W2b    = (ushort_t*)bump((size_t)64 * 64 * 2);
    int*      bsum   = (int*)bump((size_t)512 * 4);
    int*      bsum2  = (int*)bump((size_t)64 * 4);
    ushort_t* aggs   = h1;  // h1 is dead after k_gemm2

    const int* src = ei;
    const int* dst = ei + NE;

    // zero: cnt + cnt2 + pool (contiguous by layout)
    int zn = NN + NSEG + BATCH * 64 + 16;
    k_zero<<<512, 256, 0, stream>>>((float*)cnt, zn);

    // fused histograms; dinv + W2 bf16
    k_hist2<<<(NE + 255) / 256, 256, 0, stream>>>(dst, batch, depth, cnt, segn, cnt2);
    k_prep<<<(NN + 255) / 256, 256, 0, stream>>>(cnt, dinv, W2, W2b);

    // fused scans: edge-CSR offsets + node-sort offsets
    k_scan_block_f<<<NBLK_E + NBLK_S, 256, 0, stream>>>(cnt, bsum, cnt2, bsum2);
    k_scan_top_f<<<1, 512, 0, stream>>>(bsum, bsum2);
    k_scan_final_f<<<NBLK_E + NBLK_S, 256, 0, stream>>>(cnt, bsum, rowoff, cursor,
                                                        cnt2, bsum2, soff, cursor2);

    // fused reorders (edge CSR 4B payload + node sort)
    k_reorder<<<(NE + 255) / 256, 256, 0, stream>>>(src, dst, segn, cursor, esrc, cursor2, nord);

    // layer-1: CSR aggregate x + dense build (bf16 h1, post-relu), 4-way
    k_build1<<<2048, 256, 0, stream>>>(x, W1, b1, dinv, rowoff, esrc, h1);

    // layer-2 GEMM (MFMA)
    k_gemm2<<<2048, 256, 0, stream>>>(h1, W2b, xw2);

    // layer-2 aggregate (node-parallel, 8-way, seg-sorted output)
    k_agg<<<4096, 256, 0, stream>>>(xw2, b2, dinv, rowoff, esrc, nord, aggs);

    // pool (sequential over sorted rows)
    k_pool2<<<NSEG / 4, 256, 0, stream>>>(aggs, soff, sumb, mxb, cntb);

    // conv + partial mean
    k_conv<<<BATCH * 8, 256, 0, stream>>>(sumb, mxb, cntb, cw, cb, pool);

    // head
    k_head<<<BATCH, 64, 0, stream>>>(pool, f1w, f1b, f2w, f2b, out);
}

// Round 9
// 698.799 us; speedup vs baseline: 1.1050x; 1.1050x over previous
//
#include <hip/hip_runtime.h>

typedef unsigned short ushort_t;
typedef unsigned int uint_t;
typedef __attribute__((ext_vector_type(8))) short short8;
typedef __attribute__((ext_vector_type(4))) float f32x4;

#define NN 500000
#define NE 1500000
#define BATCH 64
#define LSEQ 512
#define NSEG (BATCH * LSEQ)          // 32768
#define NBLK_E ((NN + 1023) / 1024)  // 489
#define NBLK_S (NSEG / 1024)         // 32

__device__ inline float bf2f(ushort_t u) {
    union { uint_t u; float f; } c; c.u = ((uint_t)u) << 16; return c.f;
}
__device__ inline ushort_t f2bf(float f) {
    union { float f; uint_t u; } c; c.f = f;
    uint_t u = c.u;
    return (ushort_t)((u + 0x7fff + ((u >> 16) & 1)) >> 16);  // RNE
}
__device__ inline int imax(int a, int b) { return a > b ? a : b; }

// ---------------- zero a 4B-word region ----------------
__global__ void k_zero(float* __restrict__ p, int n) {
    int i = blockIdx.x * blockDim.x + threadIdx.x;
    int stride = gridDim.x * blockDim.x;
    for (; i < n; i += stride) p[i] = 0.0f;
}

// ---------------- fused: dst degree histogram (natural order) + node seg id/histogram ----
__global__ void k_hist2(const int* __restrict__ dst, const int* __restrict__ batch,
                        const int* __restrict__ depth, int* __restrict__ cnt,
                        int* __restrict__ segn, int* __restrict__ cnt2) {
    int t = blockIdx.x * blockDim.x + threadIdx.x;
    if (t < NE) {
        atomicAdd(&cnt[dst[t]], 1);
        if (t < NN) {
            int s = batch[t] * LSEQ + depth[t];
            segn[t] = s;
            atomicAdd(&cnt2[s], 1);
        }
    }
}

// ---------------- generic scan (3 kernels) ----------------
__global__ __launch_bounds__(256) void k_scan_block(const int* __restrict__ cnt,
                                                    int* __restrict__ bsum, int n) {
    __shared__ int sd[256];
    int blk = blockIdx.x, tid = threadIdx.x;
    int base = blk * 1024 + tid * 4;
    int s = 0;
#pragma unroll
    for (int k = 0; k < 4; ++k) { int i = base + k; if (i < n) s += cnt[i]; }
    sd[tid] = s;
    __syncthreads();
    for (int off = 128; off; off >>= 1) {
        if (tid < off) sd[tid] += sd[tid + off];
        __syncthreads();
    }
    if (tid == 0) bsum[blk] = sd[0];
}

__global__ __launch_bounds__(512) void k_scan_top(int* __restrict__ bsum, int nblk) {
    __shared__ int sd[512];
    int tid = threadIdx.x;
    int v = (tid < nblk) ? bsum[tid] : 0;
    sd[tid] = v;
    __syncthreads();
    for (int off = 1; off < 512; off <<= 1) {
        int t = (tid >= off) ? sd[tid - off] : 0;
        __syncthreads();
        sd[tid] += t;
        __syncthreads();
    }
    if (tid < nblk) bsum[tid] = sd[tid] - v;  // exclusive
}

__global__ __launch_bounds__(256) void k_scan_final(const int* __restrict__ cnt, const int* __restrict__ bsum,
                                                    int* __restrict__ rowoff, int* __restrict__ cursor,
                                                    int n, int total) {
    __shared__ int sd[256];
    int blk = blockIdx.x, tid = threadIdx.x;
    int base = blk * 1024 + tid * 4;
    int loc[4]; int s = 0;
#pragma unroll
    for (int k = 0; k < 4; ++k) { int i = base + k; int c = (i < n) ? cnt[i] : 0; loc[k] = s; s += c; }
    sd[tid] = s;
    __syncthreads();
    for (int off = 1; off < 256; off <<= 1) {
        int t = (tid >= off) ? sd[tid - off] : 0;
        __syncthreads();
        sd[tid] += t;
        __syncthreads();
    }
    int texc = sd[tid] - s + bsum[blk];
#pragma unroll
    for (int k = 0; k < 4; ++k) {
        int i = base + k;
        if (i < n) { int v = texc + loc[k]; rowoff[i] = v; cursor[i] = v; }
    }
    if (blk == 0 && tid == 0) rowoff[n] = total;
}

// ------- node reorder: nord (seg-sorted -> natural) and pos (natural -> seg-sorted) -------
__global__ void k_nreorder(const int* __restrict__ segn, int* __restrict__ cursor2,
                           int* __restrict__ nord, int* __restrict__ pos) {
    int n = blockIdx.x * blockDim.x + threadIdx.x;
    if (n >= NN) return;
    int p = atomicAdd(&cursor2[segn[n]], 1);
    nord[p] = n;
    pos[n] = p;
}

// ------- prep: permute degree into i-space, dinvs; W2 -> bf16 -------
__global__ void k_prep(const int* __restrict__ cnt, const int* __restrict__ nord,
                       float* __restrict__ dinvs, int* __restrict__ cntp,
                       const float* __restrict__ W2, ushort_t* __restrict__ W2b) {
    int i = blockIdx.x * blockDim.x + threadIdx.x;
    if (i < NN) {
        int dg = cnt[nord[i]];
        cntp[i] = dg;
        dinvs[i] = rsqrtf((float)dg + 1.0f);
    }
    if (i < 64 * 64) W2b[i] = f2bf(W2[i]);
}

// ------- edge reorder into i-space CSR: ep8={ps,w}, epx={w*x0[s], w*x1[s]} -------
__global__ void k_reorder(const int* __restrict__ src, const int* __restrict__ dst,
                          const int* __restrict__ pos, const float* __restrict__ dinvs,
                          const float* __restrict__ x,
                          int* __restrict__ cursor, uint2* __restrict__ ep8,
                          float2* __restrict__ epx) {
    int e = blockIdx.x * blockDim.x + threadIdx.x;
    if (e >= NE) return;
    int s = src[e], d = dst[e];
    int ps = pos[s], pd = pos[d];
    float w = dinvs[ps] * dinvs[pd];
    int q = atomicAdd(&cursor[pd], 1);
    ep8[q] = make_uint2((uint_t)ps, __float_as_uint(w));
    const float2* x2 = (const float2*)x;
    float2 xv = x2[s];
    epx[q] = make_float2(w * xv.x, w * xv.y);
}

// ------- layer-1 (i-space, fully streaming): h1s = relu(W1^T(dv^2 x[n] + sum epx) + b1) ----
__global__ void k_build1(const float* __restrict__ x, const float* __restrict__ W1,
                         const float* __restrict__ b1, const float* __restrict__ dinvs,
                         const int* __restrict__ nord, const int* __restrict__ rowoff,
                         const float2* __restrict__ epx, ushort_t* __restrict__ h1s) {
    int lane = threadIdx.x & 63;
    int wave = (blockIdx.x * blockDim.x + threadIdx.x) >> 6;
    int nwaves = (gridDim.x * blockDim.x) >> 6;
    const float2* x2 = (const float2*)x;
    float w0 = W1[lane], w1 = W1[64 + lane], bj = b1[lane];
    for (int i0 = wave * 4; i0 < NN; i0 += nwaves * 4) {   // NN % 4 == 0
        float a0[4], a1[4]; int r[4], l[4];
#pragma unroll
        for (int j = 0; j < 4; ++j) {
            int i = i0 + j;
            float dv = dinvs[i];
            float2 xv = x2[nord[i]];   // 8B gather over 4MB footprint: L2-resident
            a0[j] = dv * dv * xv.x;
            a1[j] = dv * dv * xv.y;
            r[j] = rowoff[i];
        }
#pragma unroll
        for (int j = 0; j < 4; ++j) l[j] = rowoff[i0 + j + 1] - r[j];
        int len = imax(imax(l[0], l[1]), imax(l[2], l[3]));
        for (int k = 0; k < len; ++k) {
#pragma unroll
            for (int j = 0; j < 4; ++j) {
                if (k < l[j]) {
                    float2 e = epx[r[j] + k];   // sequential
                    a0[j] += e.x;
                    a1[j] += e.y;
                }
            }
        }
#pragma unroll
        for (int j = 0; j < 4; ++j)
            h1s[(size_t)(i0 + j) * 64 + lane] = f2bf(fmaxf(a0[j] * w0 + a1[j] * w1 + bj, 0.0f));
    }
}

// ------- layer 2 GEMM via MFMA: xw2s = h1s @ W2  (i-space, bf16) -------
__global__ __launch_bounds__(256) void k_gemm2(const ushort_t* __restrict__ h1,
                                               const ushort_t* __restrict__ W2b,
                                               ushort_t* __restrict__ xw2) {
    int lane = threadIdx.x & 63;
    int wave = (blockIdx.x * blockDim.x + threadIdx.x) >> 6;
    int nwaves = (gridDim.x * blockDim.x) >> 6;
    int col = lane & 15, kg = lane >> 4;

    short8 bfrag[2][4];
#pragma unroll
    for (int t = 0; t < 2; ++t)
#pragma unroll
        for (int j = 0; j < 4; ++j)
#pragma unroll
            for (int b = 0; b < 8; ++b) {
                int k = t * 32 + kg * 8 + b;
                bfrag[t][j][b] = (short)W2b[k * 64 + j * 16 + col];
            }

    const int NT = NN / 16;  // 31250
    for (int tile = wave; tile < NT; tile += nwaves) {
        size_t base = (size_t)tile * 16 * 64;
        short8 a0 = *(const short8*)(h1 + base + (size_t)col * 64 + kg * 8);
        short8 a1 = *(const short8*)(h1 + base + (size_t)col * 64 + 32 + kg * 8);
        f32x4 acc[4];
#pragma unroll
        for (int j = 0; j < 4; ++j) {
            acc[j] = (f32x4){0.0f, 0.0f, 0.0f, 0.0f};
            acc[j] = __builtin_amdgcn_mfma_f32_16x16x32_bf16(a0, bfrag[0][j], acc[j], 0, 0, 0);
            acc[j] = __builtin_amdgcn_mfma_f32_16x16x32_bf16(a1, bfrag[1][j], acc[j], 0, 0, 0);
        }
#pragma unroll
        for (int j = 0; j < 4; ++j)
#pragma unroll
            for (int r = 0; r < 4; ++r)
                xw2[base + (size_t)(kg * 4 + r) * 64 + j * 16 + col] = f2bf(acc[j][r]);
    }
}

// ------- layer-2 aggregate + relu + pool (wave per seg, 8-way, i-space sequential) -------
__global__ __launch_bounds__(256) void k_aggpool(const ushort_t* __restrict__ xw2s,
                                                 const float* __restrict__ b2,
                                                 const float* __restrict__ dinvs,
                                                 const int* __restrict__ rowoff,
                                                 const uint2* __restrict__ ep8,
                                                 const int* __restrict__ soff,
                                                 float* __restrict__ sumb,
                                                 float* __restrict__ mxb,
                                                 float* __restrict__ cntb) {
    int lane = threadIdx.x & 63;
    int seg = (blockIdx.x * blockDim.x + threadIdx.x) >> 6;
    if (seg >= NSEG) return;
    float bj = b2[lane];
    int s0 = soff[seg], s1 = soff[seg + 1];
    float ssum = 0.0f, smax = 0.0f;
    for (int i0 = s0; i0 < s1; i0 += 8) {
        int m = s1 - i0; if (m > 8) m = 8;
        float a[8]; int r[8], l[8];
#pragma unroll
        for (int j = 0; j < 8; ++j) {
            if (j < m) {
                int i = i0 + j;
                float dv = dinvs[i];                       // sequential
                r[j] = rowoff[i]; l[j] = rowoff[i + 1] - r[j];  // sequential
                a[j] = dv * dv * bf2f(xw2s[(size_t)i * 64 + lane]) + bj;  // sequential row
            } else { r[j] = 0; l[j] = 0; a[j] = 0.0f; }
        }
        int len = 0;
#pragma unroll
        for (int j = 0; j < 8; ++j) len = imax(len, l[j]);
        for (int k = 0; k < len; ++k) {
#pragma unroll
            for (int j = 0; j < 8; ++j) {
                if (k < l[j]) {
                    uint2 p = ep8[r[j] + k];               // sequential
                    a[j] += __uint_as_float(p.y) * bf2f(xw2s[(size_t)p.x * 64 + lane]);  // the one random gather
                }
            }
        }
#pragma unroll
        for (int j = 0; j < 8; ++j) {
            if (j < m) {
                float v = fmaxf(a[j], 0.0f);
                ssum += v;
                smax = fmaxf(smax, v);
            }
        }
    }
    sumb[seg * 64 + lane] = ssum;
    mxb[seg * 64 + lane] = smax;   // 0 for empty seg: matches where(cnt>0, mx, 0)
    if (lane == 0) cntb[seg] = (float)(s1 - s0);
}

// ---------------- conv1d(k=3,pad=1) + relu + partial mean over L ----------------
__global__ __launch_bounds__(256) void k_conv(const float* __restrict__ sum,
                                              const float* __restrict__ mxf,
                                              const float* __restrict__ cnt,
                                              const float* __restrict__ cw,
                                              const float* __restrict__ cb,
                                              float* __restrict__ pooled) {
    __shared__ float s_seq[66 * 129];
    int b = blockIdx.x >> 3;
    int l0 = (blockIdx.x & 7) * 64;
    int tid = threadIdx.x;
    for (int idx = tid; idx < 66 * 128; idx += 256) {
        int r = idx >> 7, i = idx & 127;
        int l = l0 + r - 1;
        float v = 0.0f;
        if (l >= 0 && l < LSEQ) {
            int seg = b * LSEQ + l;
            if (i < 64) v = sum[seg * 64 + i] / fmaxf(cnt[seg], 1.0f);
            else        v = mxf[seg * 64 + (i - 64)];
        }
        s_seq[r * 129 + i] = v;
    }
    __syncthreads();
    int l_local = tid & 63;
    int wid = tid >> 6;
    for (int rep = 0; rep < 16; ++rep) {
        int c = __builtin_amdgcn_readfirstlane(wid + 4 * rep);
        const float* wc = cw + c * 384;
        float acc = cb[c];
#pragma unroll
        for (int kk = 0; kk < 3; ++kk) {
            const float* sr = s_seq + (l_local + kk) * 129;
#pragma unroll 8
            for (int i = 0; i < 128; ++i)
                acc += sr[i] * wc[i * 3 + kk];
        }
        float y = fmaxf(acc, 0.0f);
#pragma unroll
        for (int off = 32; off; off >>= 1) y += __shfl_xor(y, off, 64);
        if (l_local == 0) atomicAdd(&pooled[b * 64 + c], y);
    }
}

// ---------------- head ----------------
__global__ void k_head(const float* __restrict__ pooled, const float* __restrict__ f1w,
                       const float* __restrict__ f1b, const float* __restrict__ f2w,
                       const float* __restrict__ f2b, float* __restrict__ out) {
    int b = blockIdx.x;
    int j = threadIdx.x;
    const float invL = 1.0f / (float)LSEQ;
    float z = f1b[j];
    for (int c = 0; c < 64; ++c)
        z += (pooled[b * 64 + c] * invL) * f1w[c * 64 + j];
    z = fmaxf(z, 0.0f);
    float v = z * f2w[j];
#pragma unroll
    for (int off = 32; off; off >>= 1) v += __shfl_xor(v, off, 64);
    if (j == 0) out[b] = 1.0f / (1.0f + expf(-(v + f2b[0])));
}

extern "C" void kernel_launch(void* const* d_in, const int* in_sizes, int n_in,
                              void* d_out, int out_size, void* d_ws, size_t ws_size,
                              hipStream_t stream) {
    const float* x     = (const float*)d_in[0];
    const int*   ei    = (const int*)d_in[1];
    const int*   depth = (const int*)d_in[2];
    const int*   batch = (const int*)d_in[3];
    const float* W1    = (const float*)d_in[4];
    const float* b1    = (const float*)d_in[5];
    const float* W2    = (const float*)d_in[6];
    const float* b2    = (const float*)d_in[7];
    const float* cw    = (const float*)d_in[8];
    const float* cb    = (const float*)d_in[9];
    const float* f1w   = (const float*)d_in[10];
    const float* f1b   = (const float*)d_in[11];
    const float* f2w   = (const float*)d_in[12];
    const float* f2b   = (const float*)d_in[13];
    float* out = (float*)d_out;

    // ---- workspace layout (~185 MB), each chunk 16B-aligned ----
    char* p = (char*)d_ws;
    auto bump = [&p](size_t bytes) { char* r = p; p += (bytes + 15) & ~(size_t)15; return r; };
    int*      cnt    = (int*)bump((size_t)NN * 4);          // zeroed ┐
    int*      cnt2   = (int*)bump((size_t)NSEG * 4);        //        │ one k_zero
    float*    pool   = (float*)bump((size_t)BATCH * 64 * 4);// zeroed ┘
    int*      segn   = (int*)bump((size_t)NN * 4);
    int*      nord   = (int*)bump((size_t)NN * 4);
    int*      pos    = (int*)bump((size_t)NN * 4);
    int*      soff   = (int*)bump((size_t)(NSEG + 8) * 4);
    int*      cursor2= (int*)bump((size_t)NSEG * 4);
    float*    dinvs  = (float*)bump((size_t)NN * 4);
    int*      cntp   = (int*)bump((size_t)NN * 4);
    int*      rowoff = (int*)bump((size_t)(NN + 8) * 4);
    int*      cursor = (int*)bump((size_t)NN * 4);
    uint2*    ep8    = (uint2*)bump((size_t)NE * 8);
    float2*   epx    = (float2*)bump((size_t)NE * 8);
    ushort_t* h1s    = (ushort_t*)bump((size_t)NN * 128);
    ushort_t* xw2s   = (ushort_t*)bump((size_t)NN * 128);
    float*    sumb   = (float*)bump((size_t)NSEG * 64 * 4);
    float*    mxb    = (float*)bump((size_t)NSEG * 64 * 4);
    float*    cntb   = (float*)bump((size_t)NSEG * 4);
    ushort_t* W2b    = (ushort_t*)bump((size_t)64 * 64 * 2);
    int*      bsum   = (int*)bump((size_t)512 * 4);
    int*      bsum2  = (int*)bump((size_t)64 * 4);

    const int* src = ei;
    const int* dst = ei + NE;

    // zero: cnt + cnt2 + pool (contiguous by layout)
    int zn = NN + NSEG + BATCH * 64 + 16;
    k_zero<<<512, 256, 0, stream>>>((float*)cnt, zn);

    // degree (natural) + seg histograms
    k_hist2<<<(NE + 255) / 256, 256, 0, stream>>>(dst, batch, depth, cnt, segn, cnt2);

    // seg scan -> soff/cursor2 ; node reorder -> nord/pos
    k_scan_block<<<NBLK_S, 256, 0, stream>>>(cnt2, bsum2, NSEG);
    k_scan_top<<<1, 512, 0, stream>>>(bsum2, NBLK_S);
    k_scan_final<<<NBLK_S, 256, 0, stream>>>(cnt2, bsum2, soff, cursor2, NSEG, NN);
    k_nreorder<<<(NN + 255) / 256, 256, 0, stream>>>(segn, cursor2, nord, pos);

    // permute degrees into i-space; dinvs; W2 bf16
    k_prep<<<(NN + 255) / 256, 256, 0, stream>>>(cnt, nord, dinvs, cntp, W2, W2b);

    // i-space CSR offsets
    k_scan_block<<<NBLK_E, 256, 0, stream>>>(cntp, bsum, NN);
    k_scan_top<<<1, 512, 0, stream>>>(bsum, NBLK_E);
    k_scan_final<<<NBLK_E, 256, 0, stream>>>(cntp, bsum, rowoff, cursor, NN, NE);

    // edge reorder (i-space CSR, premultiplied layer-1 payload)
    k_reorder<<<(NE + 255) / 256, 256, 0, stream>>>(src, dst, pos, dinvs, x, cursor, ep8, epx);

    // layer-1 build (streaming, bf16 h1s, post-relu)
    k_build1<<<2048, 256, 0, stream>>>(x, W1, b1, dinvs, nord, rowoff, epx, h1s);

    // layer-2 GEMM (MFMA)
    k_gemm2<<<2048, 256, 0, stream>>>(h1s, W2b, xw2s);

    // layer-2 aggregate + relu + pool (fused, sequential except neighbor gathers)
    k_aggpool<<<NSEG / 4, 256, 0, stream>>>(xw2s, b2, dinvs, rowoff, ep8, soff,
                                            sumb, mxb, cntb);

    // conv + partial mean
    k_conv<<<BATCH * 8, 256, 0, stream>>>(sumb, mxb, cntb, cw, cb, pool);

    // head
    k_head<<<BATCH, 64, 0, stream>>>(pool, f1w, f1b, f2w, f2b, out);
}

// Round 11
// 577.385 us; speedup vs baseline: 1.3373x; 1.2103x over previous
//
#include <hip/hip_runtime.h>

typedef unsigned short ushort_t;
typedef unsigned int uint_t;
typedef __attribute__((ext_vector_type(8))) short short8;
typedef __attribute__((ext_vector_type(4))) float f32x4;

#define NN 500000
#define NE 1500000
#define BATCH 64
#define LSEQ 512
#define NSEG (BATCH * LSEQ)          // 32768
#define NBLK_E ((NN + 1023) / 1024)  // 489
#define NBLK_S (NSEG / 1024)         // 32

__device__ inline float bf2f(ushort_t u) {
    union { uint_t u; float f; } c; c.u = ((uint_t)u) << 16; return c.f;
}
__device__ inline ushort_t f2bf(float f) {
    union { float f; uint_t u; } c; c.f = f;
    uint_t u = c.u;
    return (ushort_t)((u + 0x7fff + ((u >> 16) & 1)) >> 16);  // RNE
}
__device__ inline int imax(int a, int b) { return a > b ? a : b; }

// ---------------- zero a 4B-word region ----------------
__global__ void k_zero(float* __restrict__ p, int n) {
    int i = blockIdx.x * blockDim.x + threadIdx.x;
    int stride = gridDim.x * blockDim.x;
    for (; i < n; i += stride) p[i] = 0.0f;
}

// ---------------- fused: dst degree histogram (natural) + node seg id/histogram ----------
__global__ void k_hist2(const int* __restrict__ dst, const int* __restrict__ batch,
                        const int* __restrict__ depth, int* __restrict__ cnt,
                        int* __restrict__ segn, int* __restrict__ cnt2) {
    int t = blockIdx.x * blockDim.x + threadIdx.x;
    if (t < NE) {
        atomicAdd(&cnt[dst[t]], 1);
        if (t < NN) {
            int s = batch[t] * LSEQ + depth[t];
            segn[t] = s;
            atomicAdd(&cnt2[s], 1);
        }
    }
}

// ---------------- generic scan (3 kernels) ----------------
__global__ __launch_bounds__(256) void k_scan_block(const int* __restrict__ cnt,
                                                    int* __restrict__ bsum, int n) {
    __shared__ int sd[256];
    int blk = blockIdx.x, tid = threadIdx.x;
    int base = blk * 1024 + tid * 4;
    int s = 0;
#pragma unroll
    for (int k = 0; k < 4; ++k) { int i = base + k; if (i < n) s += cnt[i]; }
    sd[tid] = s;
    __syncthreads();
    for (int off = 128; off; off >>= 1) {
        if (tid < off) sd[tid] += sd[tid + off];
        __syncthreads();
    }
    if (tid == 0) bsum[blk] = sd[0];
}

__global__ __launch_bounds__(512) void k_scan_top(int* __restrict__ bsum, int nblk) {
    __shared__ int sd[512];
    int tid = threadIdx.x;
    int v = (tid < nblk) ? bsum[tid] : 0;
    sd[tid] = v;
    __syncthreads();
    for (int off = 1; off < 512; off <<= 1) {
        int t = (tid >= off) ? sd[tid - off] : 0;
        __syncthreads();
        sd[tid] += t;
        __syncthreads();
    }
    if (tid < nblk) bsum[tid] = sd[tid] - v;  // exclusive
}

__global__ __launch_bounds__(256) void k_scan_final(const int* __restrict__ cnt, const int* __restrict__ bsum,
                                                    int* __restrict__ rowoff, int* __restrict__ cursor,
                                                    int n, int total) {
    __shared__ int sd[256];
    int blk = blockIdx.x, tid = threadIdx.x;
    int base = blk * 1024 + tid * 4;
    int loc[4]; int s = 0;
#pragma unroll
    for (int k = 0; k < 4; ++k) { int i = base + k; int c = (i < n) ? cnt[i] : 0; loc[k] = s; s += c; }
    sd[tid] = s;
    __syncthreads();
    for (int off = 1; off < 256; off <<= 1) {
        int t = (tid >= off) ? sd[tid - off] : 0;
        __syncthreads();
        sd[tid] += t;
        __syncthreads();
    }
    int texc = sd[tid] - s + bsum[blk];
#pragma unroll
    for (int k = 0; k < 4; ++k) {
        int i = base + k;
        if (i < n) { int v = texc + loc[k]; rowoff[i] = v; cursor[i] = v; }
    }
    if (blk == 0 && tid == 0) rowoff[n] = total;
}

// ------- node reorder: nord (seg-sorted -> natural) and pos (natural -> seg-sorted) -------
__global__ void k_nreorder(const int* __restrict__ segn, int* __restrict__ cursor2,
                           int* __restrict__ nord, int* __restrict__ pos) {
    int n = blockIdx.x * blockDim.x + threadIdx.x;
    if (n >= NN) return;
    int p = atomicAdd(&cursor2[segn[n]], 1);
    nord[p] = n;
    pos[n] = p;
}

// ------- prep: permute degree into i-space, dinvs; W2 -> bf16 -------
__global__ void k_prep(const int* __restrict__ cnt, const int* __restrict__ nord,
                       float* __restrict__ dinvs, int* __restrict__ cntp,
                       const float* __restrict__ W2, ushort_t* __restrict__ W2b) {
    int i = blockIdx.x * blockDim.x + threadIdx.x;
    if (i < NN) {
        int dg = cnt[nord[i]];
        cntp[i] = dg;
        dinvs[i] = rsqrtf((float)dg + 1.0f);
    }
    if (i < 64 * 64) W2b[i] = f2bf(W2[i]);
}

// ------- edge reorder into i-space CSR: ONE 16B record {ps|loc<<20, w, w*x0, w*x1} -------
__global__ void k_reorder(const int* __restrict__ src, const int* __restrict__ dst,
                          const int* __restrict__ pos, const float* __restrict__ dinvs,
                          const float* __restrict__ x,
                          int* __restrict__ cursor, uint4* __restrict__ epk) {
    int e = blockIdx.x * blockDim.x + threadIdx.x;
    if (e >= NE) return;
    int s = src[e], d = dst[e];
    int ps = pos[s], pd = pos[d];
    float w = dinvs[ps] * dinvs[pd];
    int q = atomicAdd(&cursor[pd], 1);
    const float2* x2 = (const float2*)x;
    float2 xv = x2[s];
    epk[q] = make_uint4((uint_t)ps | ((uint_t)(pd & 15) << 20), __float_as_uint(w),
                        __float_as_uint(w * xv.x), __float_as_uint(w * xv.y));
}

// ------- layer-1 (i-space, streaming): h1s = relu(W1^T(dv^2 x[n] + sum epk.zw) + b1) ----
__global__ void k_build1(const float* __restrict__ x, const float* __restrict__ W1,
                         const float* __restrict__ b1, const float* __restrict__ dinvs,
                         const int* __restrict__ nord, const int* __restrict__ rowoff,
                         const uint4* __restrict__ epk, ushort_t* __restrict__ h1s) {
    int lane = threadIdx.x & 63;
    int wave = (blockIdx.x * blockDim.x + threadIdx.x) >> 6;
    int nwaves = (gridDim.x * blockDim.x) >> 6;
    const float2* x2 = (const float2*)x;
    float w0 = W1[lane], w1 = W1[64 + lane], bj = b1[lane];
    for (int i0 = wave * 4; i0 < NN; i0 += nwaves * 4) {   // NN % 4 == 0
        float a0[4], a1[4]; int r[4], l[4];
#pragma unroll
        for (int j = 0; j < 4; ++j) {
            int i = i0 + j;
            float dv = dinvs[i];
            float2 xv = x2[nord[i]];   // 8B gather over 4MB footprint: L2-resident
            a0[j] = dv * dv * xv.x;
            a1[j] = dv * dv * xv.y;
            r[j] = rowoff[i];
        }
#pragma unroll
        for (int j = 0; j < 4; ++j) l[j] = rowoff[i0 + j + 1] - r[j];
        int len = imax(imax(l[0], l[1]), imax(l[2], l[3]));
        for (int k = 0; k < len; ++k) {
#pragma unroll
            for (int j = 0; j < 4; ++j) {
                if (k < l[j]) {
                    uint4 ek = epk[r[j] + k];   // sequential
                    a0[j] += __uint_as_float(ek.z);
                    a1[j] += __uint_as_float(ek.w);
                }
            }
        }
#pragma unroll
        for (int j = 0; j < 4; ++j)
            h1s[(size_t)(i0 + j) * 64 + lane] = f2bf(fmaxf(a0[j] * w0 + a1[j] * w1 + bj, 0.0f));
    }
}

// ------- layer 2 GEMM via MFMA: xw2s = h1s @ W2  (i-space, bf16) -------
__global__ __launch_bounds__(256) void k_gemm2(const ushort_t* __restrict__ h1,
                                               const ushort_t* __restrict__ W2b,
                                               ushort_t* __restrict__ xw2) {
    int lane = threadIdx.x & 63;
    int wave = (blockIdx.x * blockDim.x + threadIdx.x) >> 6;
    int nwaves = (gridDim.x * blockDim.x) >> 6;
    int col = lane & 15, kg = lane >> 4;

    short8 bfrag[2][4];
#pragma unroll
    for (int t = 0; t < 2; ++t)
#pragma unroll
        for (int j = 0; j < 4; ++j)
#pragma unroll
            for (int b = 0; b < 8; ++b) {
                int k = t * 32 + kg * 8 + b;
                bfrag[t][j][b] = (short)W2b[k * 64 + j * 16 + col];
            }

    const int NT = NN / 16;  // 31250
    for (int tile = wave; tile < NT; tile += nwaves) {
        size_t base = (size_t)tile * 16 * 64;
        short8 a0 = *(const short8*)(h1 + base + (size_t)col * 64 + kg * 8);
        short8 a1 = *(const short8*)(h1 + base + (size_t)col * 64 + 32 + kg * 8);
        f32x4 acc[4];
#pragma unroll
        for (int j = 0; j < 4; ++j) {
            acc[j] = (f32x4){0.0f, 0.0f, 0.0f, 0.0f};
            acc[j] = __builtin_amdgcn_mfma_f32_16x16x32_bf16(a0, bfrag[0][j], acc[j], 0, 0, 0);
            acc[j] = __builtin_amdgcn_mfma_f32_16x16x32_bf16(a1, bfrag[1][j], acc[j], 0, 0, 0);
        }
#pragma unroll
        for (int j = 0; j < 4; ++j)
#pragma unroll
            for (int r = 0; r < 4; ++r)
                xw2[base + (size_t)(kg * 4 + r) * 64 + j * 16 + col] = f2bf(acc[j][r]);
    }
}

// ------- layer-2 aggregate: wave per 16-node tile, FLAT edge loop, LDS accumulators ------
// aggs[i] = relu( dv^2*xw2s[i] + b2 + sum_e w*xw2s[ps] ), bf16
__global__ __launch_bounds__(256) void k_agg3(const ushort_t* __restrict__ xw2s,
                                              const float* __restrict__ b2,
                                              const float* __restrict__ dinvs,
                                              const int* __restrict__ rowoff,
                                              const uint4* __restrict__ epk,
                                              ushort_t* __restrict__ aggs) {
    __shared__ float accs[4][16][64];   // per-wave tile accumulator (16 KB/block)
    int lane = threadIdx.x & 63;
    int wid = threadIdx.x >> 6;
    int wave = (blockIdx.x * blockDim.x + threadIdx.x) >> 6;
    int nwaves = (gridDim.x * blockDim.x) >> 6;
    float bj = b2[lane];
    float (*a)[64] = accs[wid];
    const int NT = NN / 16;  // 31250
    for (int t = wave; t < NT; t += nwaves) {
        int i0 = t * 16;
        // init: self term + bias (sequential rows)
#pragma unroll
        for (int j = 0; j < 16; ++j) {
            int i = i0 + j;
            float dv = dinvs[i];
            a[j][lane] = dv * dv * bf2f(xw2s[(size_t)i * 64 + lane]) + bj;
        }
        int e = rowoff[i0], e1 = rowoff[i0 + 16];
        // flat 8-deep edge loop: work ∝ sum(deg), 8 independent gathers in flight
        for (; e + 8 <= e1; e += 8) {
            uint4 p[8];
#pragma unroll
            for (int jj = 0; jj < 8; ++jj) p[jj] = epk[e + jj];        // sequential
            float v[8];
#pragma unroll
            for (int jj = 0; jj < 8; ++jj)
                v[jj] = __uint_as_float(p[jj].y) *
                        bf2f(xw2s[(size_t)(p[jj].x & 0xFFFFFu) * 64 + lane]);  // random gather
#pragma unroll
            for (int jj = 0; jj < 8; ++jj)
                a[p[jj].x >> 20][lane] += v[jj];                        // LDS RMW (sequential ops)
        }
        for (; e < e1; ++e) {
            uint4 p = epk[e];
            a[p.x >> 20][lane] += __uint_as_float(p.y) *
                                  bf2f(xw2s[(size_t)(p.x & 0xFFFFFu) * 64 + lane]);
        }
        // writeout (sequential)
#pragma unroll
        for (int j = 0; j < 16; ++j)
            aggs[(size_t)(i0 + j) * 64 + lane] = f2bf(fmaxf(a[j][lane], 0.0f));
    }
}

// ------- pool: wave per seg, sequential reads of seg-sorted agg rows -------
__global__ __launch_bounds__(256) void k_pool2(const ushort_t* __restrict__ aggs,
                                               const int* __restrict__ soff,
                                               float* __restrict__ sumb,
                                               float* __restrict__ mxb,
                                               float* __restrict__ cntb) {
    int lane = threadIdx.x & 63;
    int seg = (blockIdx.x * blockDim.x + threadIdx.x) >> 6;
    if (seg >= NSEG) return;
    int i0 = soff[seg], i1 = soff[seg + 1];
    float ss = 0.0f, sm = 0.0f;
    for (int i = i0; i < i1; ++i) {
        float v = bf2f(aggs[(size_t)i * 64 + lane]);
        ss += v;
        sm = fmaxf(sm, v);
    }
    sumb[seg * 64 + lane] = ss;
    mxb[seg * 64 + lane] = sm;   // 0 for empty seg: matches where(cnt>0, mx, 0)
    if (lane == 0) cntb[seg] = (float)(i1 - i0);
}

// ---------------- conv1d(k=3,pad=1) + relu + partial mean over L ----------------
__global__ __launch_bounds__(256) void k_conv(const float* __restrict__ sum,
                                              const float* __restrict__ mxf,
                                              const float* __restrict__ cnt,
                                              const float* __restrict__ cw,
                                              const float* __restrict__ cb,
                                              float* __restrict__ pooled) {
    __shared__ float s_seq[66 * 129];
    int b = blockIdx.x >> 3;
    int l0 = (blockIdx.x & 7) * 64;
    int tid = threadIdx.x;
    for (int idx = tid; idx < 66 * 128; idx += 256) {
        int r = idx >> 7, i = idx & 127;
        int l = l0 + r - 1;
        float v = 0.0f;
        if (l >= 0 && l < LSEQ) {
            int seg = b * LSEQ + l;
            if (i < 64) v = sum[seg * 64 + i] / fmaxf(cnt[seg], 1.0f);
            else        v = mxf[seg * 64 + (i - 64)];
        }
        s_seq[r * 129 + i] = v;
    }
    __syncthreads();
    int l_local = tid & 63;
    int wid = tid >> 6;
    for (int rep = 0; rep < 16; ++rep) {
        int c = __builtin_amdgcn_readfirstlane(wid + 4 * rep);
        const float* wc = cw + c * 384;
        float acc = cb[c];
#pragma unroll
        for (int kk = 0; kk < 3; ++kk) {
            const float* sr = s_seq + (l_local + kk) * 129;
#pragma unroll 8
            for (int i = 0; i < 128; ++i)
                acc += sr[i] * wc[i * 3 + kk];
        }
        float y = fmaxf(acc, 0.0f);
#pragma unroll
        for (int off = 32; off; off >>= 1) y += __shfl_xor(y, off, 64);
        if (l_local == 0) atomicAdd(&pooled[b * 64 + c], y);
    }
}

// ---------------- head ----------------
__global__ void k_head(const float* __restrict__ pooled, const float* __restrict__ f1w,
                       const float* __restrict__ f1b, const float* __restrict__ f2w,
                       const float* __restrict__ f2b, float* __restrict__ out) {
    int b = blockIdx.x;
    int j = threadIdx.x;
    const float invL = 1.0f / (float)LSEQ;
    float z = f1b[j];
    for (int c = 0; c < 64; ++c)
        z += (pooled[b * 64 + c] * invL) * f1w[c * 64 + j];
    z = fmaxf(z, 0.0f);
    float v = z * f2w[j];
#pragma unroll
    for (int off = 32; off; off >>= 1) v += __shfl_xor(v, off, 64);
    if (j == 0) out[b] = 1.0f / (1.0f + expf(-(v + f2b[0])));
}

extern "C" void kernel_launch(void* const* d_in, const int* in_sizes, int n_in,
                              void* d_out, int out_size, void* d_ws, size_t ws_size,
                              hipStream_t stream) {
    const float* x     = (const float*)d_in[0];
    const int*   ei    = (const int*)d_in[1];
    const int*   depth = (const int*)d_in[2];
    const int*   batch = (const int*)d_in[3];
    const float* W1    = (const float*)d_in[4];
    const float* b1    = (const float*)d_in[5];
    const float* W2    = (const float*)d_in[6];
    const float* b2    = (const float*)d_in[7];
    const float* cw    = (const float*)d_in[8];
    const float* cb    = (const float*)d_in[9];
    const float* f1w   = (const float*)d_in[10];
    const float* f1b   = (const float*)d_in[11];
    const float* f2w   = (const float*)d_in[12];
    const float* f2b   = (const float*)d_in[13];
    float* out = (float*)d_out;

    // ---- workspace layout (~190 MB), each chunk 16B-aligned ----
    char* p = (char*)d_ws;
    auto bump = [&p](size_t bytes) { char* r = p; p += (bytes + 15) & ~(size_t)15; return r; };
    int*      cnt    = (int*)bump((size_t)NN * 4);          // zeroed ┐
    int*      cnt2   = (int*)bump((size_t)NSEG * 4);        //        │ one k_zero
    float*    pool   = (float*)bump((size_t)BATCH * 64 * 4);// zeroed ┘
    int*      segn   = (int*)bump((size_t)NN * 4);
    int*      nord   = (int*)bump((size_t)NN * 4);
    int*      pos    = (int*)bump((size_t)NN * 4);
    int*      soff   = (int*)bump((size_t)(NSEG + 8) * 4);
    int*      cursor2= (int*)bump((size_t)NSEG * 4);
    float*    dinvs  = (float*)bump((size_t)NN * 4);
    int*      cntp   = (int*)bump((size_t)NN * 4);
    int*      rowoff = (int*)bump((size_t)(NN + 8) * 4);
    int*      cursor = (int*)bump((size_t)NN * 4);
    uint4*    epk    = (uint4*)bump((size_t)NE * 16);
    ushort_t* h1s    = (ushort_t*)bump((size_t)NN * 128);   // reused as aggs after gemm2
    ushort_t* xw2s   = (ushort_t*)bump((size_t)NN * 128);
    float*    sumb   = (float*)bump((size_t)NSEG * 64 * 4);
    float*    mxb    = (float*)bump((size_t)NSEG * 64 * 4);
    float*    cntb   = (float*)bump((size_t)NSEG * 4);
    ushort_t* W2b    = (ushort_t*)bump((size_t)64 * 64 * 2);
    int*      bsum   = (int*)bump((size_t)512 * 4);
    int*      bsum2  = (int*)bump((size_t)64 * 4);
    ushort_t* aggs   = h1s;  // h1s dead after k_gemm2

    const int* src = ei;
    const int* dst = ei + NE;

    // zero: cnt + cnt2 + pool (contiguous by layout)
    int zn = NN + NSEG + BATCH * 64 + 16;
    k_zero<<<512, 256, 0, stream>>>((float*)cnt, zn);

    // degree (natural) + seg histograms
    k_hist2<<<(NE + 255) / 256, 256, 0, stream>>>(dst, batch, depth, cnt, segn, cnt2);

    // seg scan -> soff/cursor2 ; node reorder -> nord/pos
    k_scan_block<<<NBLK_S, 256, 0, stream>>>(cnt2, bsum2, NSEG);
    k_scan_top<<<1, 512, 0, stream>>>(bsum2, NBLK_S);
    k_scan_final<<<NBLK_S, 256, 0, stream>>>(cnt2, bsum2, soff, cursor2, NSEG, NN);
    k_nreorder<<<(NN + 255) / 256, 256, 0, stream>>>(segn, cursor2, nord, pos);

    // permute degrees into i-space; dinvs; W2 bf16
    k_prep<<<(NN + 255) / 256, 256, 0, stream>>>(cnt, nord, dinvs, cntp, W2, W2b);

    // i-space CSR offsets
    k_scan_block<<<NBLK_E, 256, 0, stream>>>(cntp, bsum, NN);
    k_scan_top<<<1, 512, 0, stream>>>(bsum, NBLK_E);
    k_scan_final<<<NBLK_E, 256, 0, stream>>>(cntp, bsum, rowoff, cursor, NN, NE);

    // edge reorder (single 16B record per edge)
    k_reorder<<<(NE + 255) / 256, 256, 0, stream>>>(src, dst, pos, dinvs, x, cursor, epk);

    // layer-1 build (streaming, bf16 h1s, post-relu)
    k_build1<<<2048, 256, 0, stream>>>(x, W1, b1, dinvs, nord, rowoff, epk, h1s);

    // layer-2 GEMM (MFMA)
    k_gemm2<<<2048, 256, 0, stream>>>(h1s, W2b, xw2s);

    // layer-2 aggregate (flat edge loop, LDS accumulators)
    k_agg3<<<4096, 256, 0, stream>>>(xw2s, b2, dinvs, rowoff, epk, aggs);

    // pool (sequential over seg-sorted rows)
    k_pool2<<<NSEG / 4, 256, 0, stream>>>(aggs, soff, sumb, mxb, cntb);

    // conv + partial mean
    k_conv<<<BATCH * 8, 256, 0, stream>>>(sumb, mxb, cntb, cw, cb, pool);

    // head
    k_head<<<BATCH, 64, 0, stream>>>(pool, f1w, f1b, f2w, f2b, out);
}

// Round 13
// 464.136 us; speedup vs baseline: 1.6636x; 1.2440x over previous
//
#include <hip/hip_runtime.h>

typedef unsigned short ushort_t;
typedef unsigned int uint_t;
typedef __attribute__((ext_vector_type(8))) short short8;
typedef __attribute__((ext_vector_type(4))) float f32x4;

#define NN 500000
#define NE 1500000
#define BATCH 64
#define LSEQ 512
#define NSEG (BATCH * LSEQ)          // 32768
#define NBLK_E ((NN + 1023) / 1024)  // 489
#define NBLK_S (NSEG / 1024)         // 32
#define SEQROW 514                   // 512 + 2 zero pad rows
#define WPKN (3 * 4 * 4 * 512)       // 24576 packed conv-weight bf16

__device__ inline float bf2f(ushort_t u) {
    union { uint_t u; float f; } c; c.u = ((uint_t)u) << 16; return c.f;
}
__device__ inline ushort_t f2bf(float f) {
    union { float f; uint_t u; } c; c.f = f;
    uint_t u = c.u;
    return (ushort_t)((u + 0x7fff + ((u >> 16) & 1)) >> 16);  // RNE
}
__device__ inline int imax(int a, int b) { return a > b ? a : b; }

// ---------------- zero a 4B-word region ----------------
__global__ void k_zero(float* __restrict__ p, int n) {
    int i = blockIdx.x * blockDim.x + threadIdx.x;
    int stride = gridDim.x * blockDim.x;
    for (; i < n; i += stride) p[i] = 0.0f;
}

// ---------------- fused: dst degree histogram (natural) + node seg id/histogram ----------
__global__ void k_hist2(const int* __restrict__ dst, const int* __restrict__ batch,
                        const int* __restrict__ depth, int* __restrict__ cnt,
                        int* __restrict__ segn, int* __restrict__ cnt2) {
    int t = blockIdx.x * blockDim.x + threadIdx.x;
    if (t < NE) {
        atomicAdd(&cnt[dst[t]], 1);
        if (t < NN) {
            int s = batch[t] * LSEQ + depth[t];
            segn[t] = s;
            atomicAdd(&cnt2[s], 1);
        }
    }
}

// ---------------- generic scan (3 kernels) ----------------
__global__ __launch_bounds__(256) void k_scan_block(const int* __restrict__ cnt,
                                                    int* __restrict__ bsum, int n) {
    __shared__ int sd[256];
    int blk = blockIdx.x, tid = threadIdx.x;
    int base = blk * 1024 + tid * 4;
    int s = 0;
#pragma unroll
    for (int k = 0; k < 4; ++k) { int i = base + k; if (i < n) s += cnt[i]; }
    sd[tid] = s;
    __syncthreads();
    for (int off = 128; off; off >>= 1) {
        if (tid < off) sd[tid] += sd[tid + off];
        __syncthreads();
    }
    if (tid == 0) bsum[blk] = sd[0];
}

__global__ __launch_bounds__(512) void k_scan_top(int* __restrict__ bsum, int nblk) {
    __shared__ int sd[512];
    int tid = threadIdx.x;
    int v = (tid < nblk) ? bsum[tid] : 0;
    sd[tid] = v;
    __syncthreads();
    for (int off = 1; off < 512; off <<= 1) {
        int t = (tid >= off) ? sd[tid - off] : 0;
        __syncthreads();
        sd[tid] += t;
        __syncthreads();
    }
    if (tid < nblk) bsum[tid] = sd[tid] - v;  // exclusive
}

__global__ __launch_bounds__(256) void k_scan_final(const int* __restrict__ cnt, const int* __restrict__ bsum,
                                                    int* __restrict__ rowoff, int* __restrict__ cursor,
                                                    int n, int total) {
    __shared__ int sd[256];
    int blk = blockIdx.x, tid = threadIdx.x;
    int base = blk * 1024 + tid * 4;
    int loc[4]; int s = 0;
#pragma unroll
    for (int k = 0; k < 4; ++k) { int i = base + k; int c = (i < n) ? cnt[i] : 0; loc[k] = s; s += c; }
    sd[tid] = s;
    __syncthreads();
    for (int off = 1; off < 256; off <<= 1) {
        int t = (tid >= off) ? sd[tid - off] : 0;
        __syncthreads();
        sd[tid] += t;
        __syncthreads();
    }
    int texc = sd[tid] - s + bsum[blk];
#pragma unroll
    for (int k = 0; k < 4; ++k) {
        int i = base + k;
        if (i < n) { int v = texc + loc[k]; rowoff[i] = v; cursor[i] = v; }
    }
    if (blk == 0 && tid == 0) rowoff[n] = total;
}

// ------- node reorder: nord (seg-sorted -> natural) and pos (natural -> seg-sorted) -------
__global__ void k_nreorder(const int* __restrict__ segn, int* __restrict__ cursor2,
                           int* __restrict__ nord, int* __restrict__ pos) {
    int n = blockIdx.x * blockDim.x + threadIdx.x;
    if (n >= NN) return;
    int p = atomicAdd(&cursor2[segn[n]], 1);
    nord[p] = n;
    pos[n] = p;
}

// ------- prep: permute degree into i-space, dinvs; W2 -> bf16; conv W -> frag-packed bf16 -
__global__ void k_prep(const int* __restrict__ cnt, const int* __restrict__ nord,
                       float* __restrict__ dinvs, int* __restrict__ cntp,
                       const float* __restrict__ W2, ushort_t* __restrict__ W2b,
                       const float* __restrict__ cw, ushort_t* __restrict__ wpk) {
    int i = blockIdx.x * blockDim.x + threadIdx.x;
    if (i < NN) {
        int dg = cnt[nord[i]];
        cntp[i] = dg;
        dinvs[i] = rsqrtf((float)dg + 1.0f);
    }
    if (i < 64 * 64) W2b[i] = f2bf(W2[i]);
    if (i < WPKN) {
        // wpk[((tap*4+kk)*4+ct)*512 + ln*8 + bq] = cw[c*384 + ii*3 + tap]
        int bq = i & 7, ln = (i >> 3) & 63, ct = (i >> 9) & 3, kk = (i >> 11) & 3, tap = i >> 13;
        int c = ct * 16 + (ln & 15);
        int ii = kk * 32 + (ln >> 4) * 8 + bq;
        wpk[i] = f2bf(cw[c * 384 + ii * 3 + tap]);
    }
}

// ------- edge reorder into i-space CSR: ONE 16B record {ps|loc<<20, w, w*x0, w*x1} -------
__global__ void k_reorder(const int* __restrict__ src, const int* __restrict__ dst,
                          const int* __restrict__ pos, const float* __restrict__ dinvs,
                          const float* __restrict__ x,
                          int* __restrict__ cursor, uint4* __restrict__ epk) {
    int e = blockIdx.x * blockDim.x + threadIdx.x;
    if (e >= NE) return;
    int s = src[e], d = dst[e];
    int ps = pos[s], pd = pos[d];
    float w = dinvs[ps] * dinvs[pd];
    int q = atomicAdd(&cursor[pd], 1);
    const float2* x2 = (const float2*)x;
    float2 xv = x2[s];
    epk[q] = make_uint4((uint_t)ps | ((uint_t)(pd & 15) << 20), __float_as_uint(w),
                        __float_as_uint(w * xv.x), __float_as_uint(w * xv.y));
}

// ------- layer-1 (i-space, streaming): h1s = relu(W1^T(dv^2 x[n] + sum epk.zw) + b1) ----
__global__ void k_build1(const float* __restrict__ x, const float* __restrict__ W1,
                         const float* __restrict__ b1, const float* __restrict__ dinvs,
                         const int* __restrict__ nord, const int* __restrict__ rowoff,
                         const uint4* __restrict__ epk, ushort_t* __restrict__ h1s) {
    int lane = threadIdx.x & 63;
    int wave = (blockIdx.x * blockDim.x + threadIdx.x) >> 6;
    int nwaves = (gridDim.x * blockDim.x) >> 6;
    const float2* x2 = (const float2*)x;
    float w0 = W1[lane], w1 = W1[64 + lane], bj = b1[lane];
    for (int i0 = wave * 4; i0 < NN; i0 += nwaves * 4) {   // NN % 4 == 0
        float a0[4], a1[4]; int r[4], l[4];
#pragma unroll
        for (int j = 0; j < 4; ++j) {
            int i = i0 + j;
            float dv = dinvs[i];
            float2 xv = x2[nord[i]];   // 8B gather over 4MB footprint: L2-resident
            a0[j] = dv * dv * xv.x;
            a1[j] = dv * dv * xv.y;
            r[j] = rowoff[i];
        }
#pragma unroll
        for (int j = 0; j < 4; ++j) l[j] = rowoff[i0 + j + 1] - r[j];
        int len = imax(imax(l[0], l[1]), imax(l[2], l[3]));
        for (int k = 0; k < len; ++k) {
#pragma unroll
            for (int j = 0; j < 4; ++j) {
                if (k < l[j]) {
                    uint4 ek = epk[r[j] + k];   // sequential
                    a0[j] += __uint_as_float(ek.z);
                    a1[j] += __uint_as_float(ek.w);
                }
            }
        }
#pragma unroll
        for (int j = 0; j < 4; ++j)
            h1s[(size_t)(i0 + j) * 64 + lane] = f2bf(fmaxf(a0[j] * w0 + a1[j] * w1 + bj, 0.0f));
    }
}

// ------- layer 2 GEMM via MFMA: xw2s = h1s @ W2  (i-space, bf16) -------
__global__ __launch_bounds__(256) void k_gemm2(const ushort_t* __restrict__ h1,
                                               const ushort_t* __restrict__ W2b,
                                               ushort_t* __restrict__ xw2) {
    int lane = threadIdx.x & 63;
    int wave = (blockIdx.x * blockDim.x + threadIdx.x) >> 6;
    int nwaves = (gridDim.x * blockDim.x) >> 6;
    int col = lane & 15, kg = lane >> 4;

    short8 bfrag[2][4];
#pragma unroll
    for (int t = 0; t < 2; ++t)
#pragma unroll
        for (int j = 0; j < 4; ++j)
#pragma unroll
            for (int b = 0; b < 8; ++b) {
                int k = t * 32 + kg * 8 + b;
                bfrag[t][j][b] = (short)W2b[k * 64 + j * 16 + col];
            }

    const int NT = NN / 16;  // 31250
    for (int tile = wave; tile < NT; tile += nwaves) {
        size_t base = (size_t)tile * 16 * 64;
        short8 a0 = *(const short8*)(h1 + base + (size_t)col * 64 + kg * 8);
        short8 a1 = *(const short8*)(h1 + base + (size_t)col * 64 + 32 + kg * 8);
        f32x4 acc[4];
#pragma unroll
        for (int j = 0; j < 4; ++j) {
            acc[j] = (f32x4){0.0f, 0.0f, 0.0f, 0.0f};
            acc[j] = __builtin_amdgcn_mfma_f32_16x16x32_bf16(a0, bfrag[0][j], acc[j], 0, 0, 0);
            acc[j] = __builtin_amdgcn_mfma_f32_16x16x32_bf16(a1, bfrag[1][j], acc[j], 0, 0, 0);
        }
#pragma unroll
        for (int j = 0; j < 4; ++j)
#pragma unroll
            for (int r = 0; r < 4; ++r)
                xw2[base + (size_t)(kg * 4 + r) * 64 + j * 16 + col] = f2bf(acc[j][r]);
    }
}

// ------- layer-2 aggregate: wave per 16-node tile, FLAT edge loop, LDS accumulators ------
__global__ __launch_bounds__(256) void k_agg3(const ushort_t* __restrict__ xw2s,
                                              const float* __restrict__ b2,
                                              const float* __restrict__ dinvs,
                                              const int* __restrict__ rowoff,
                                              const uint4* __restrict__ epk,
                                              ushort_t* __restrict__ aggs) {
    __shared__ float accs[4][16][64];   // per-wave tile accumulator (16 KB/block)
    int lane = threadIdx.x & 63;
    int wid = threadIdx.x >> 6;
    int wave = (blockIdx.x * blockDim.x + threadIdx.x) >> 6;
    int nwaves = (gridDim.x * blockDim.x) >> 6;
    float bj = b2[lane];
    float (*a)[64] = accs[wid];
    const int NT = NN / 16;  // 31250
    for (int t = wave; t < NT; t += nwaves) {
        int i0 = t * 16;
#pragma unroll
        for (int j = 0; j < 16; ++j) {
            int i = i0 + j;
            float dv = dinvs[i];
            a[j][lane] = dv * dv * bf2f(xw2s[(size_t)i * 64 + lane]) + bj;
        }
        int e = rowoff[i0], e1 = rowoff[i0 + 16];
        for (; e + 8 <= e1; e += 8) {
            uint4 p[8];
#pragma unroll
            for (int jj = 0; jj < 8; ++jj) p[jj] = epk[e + jj];        // sequential
            float v[8];
#pragma unroll
            for (int jj = 0; jj < 8; ++jj)
                v[jj] = __uint_as_float(p[jj].y) *
                        bf2f(xw2s[(size_t)(p[jj].x & 0xFFFFFu) * 64 + lane]);  // random gather
#pragma unroll
            for (int jj = 0; jj < 8; ++jj)
                a[p[jj].x >> 20][lane] += v[jj];                        // LDS RMW
        }
        for (; e < e1; ++e) {
            uint4 p = epk[e];
            a[p.x >> 20][lane] += __uint_as_float(p.y) *
                                  bf2f(xw2s[(size_t)(p.x & 0xFFFFFu) * 64 + lane]);
        }
#pragma unroll
        for (int j = 0; j < 16; ++j)
            aggs[(size_t)(i0 + j) * 64 + lane] = f2bf(fmaxf(a[j][lane], 0.0f));
    }
}

// ------- pool: wave per seg, sequential reads; emits bf16 padded seq [b][514][128] -------
__global__ __launch_bounds__(256) void k_pool2(const ushort_t* __restrict__ aggs,
                                               const int* __restrict__ soff,
                                               ushort_t* __restrict__ seqb) {
    int lane = threadIdx.x & 63;
    int seg = (blockIdx.x * blockDim.x + threadIdx.x) >> 6;
    if (seg >= NSEG) return;
    int i0 = soff[seg], i1 = soff[seg + 1];
    float ss = 0.0f, sm = 0.0f;
    for (int i = i0; i < i1; ++i) {
        float v = bf2f(aggs[(size_t)i * 64 + lane]);
        ss += v;
        sm = fmaxf(sm, v);
    }
    float mean = ss / fmaxf((float)(i1 - i0), 1.0f);   // empty seg -> 0/1 = 0
    size_t row = (size_t)(seg >> 9) * SEQROW + 1 + (seg & 511);
    seqb[row * 128 + lane] = f2bf(mean);
    seqb[row * 128 + 64 + lane] = f2bf(sm);            // empty seg max = 0 matches ref
}

// ------- conv1d(k=3,pad=1)+bias+relu+sum over L via MFMA; atomics into pooled -------
// Y^T[l,c] = sum_{tap,i} seq[l+tap-1, i] * W[c,i,tap]; A=seq rows, B=wpk frags.
__global__ __launch_bounds__(256) void k_convm(const ushort_t* __restrict__ seqb,
                                               const ushort_t* __restrict__ wpk,
                                               const float* __restrict__ cb,
                                               float* __restrict__ pooled) {
    int lane = threadIdx.x & 63;
    int gw = (blockIdx.x * blockDim.x + threadIdx.x) >> 6;   // 0..1023
    int b = gw >> 4;
    int l0base = (gw & 15) * 32;
    int col = lane & 15, kg = lane >> 4;
    float cbv[4];
#pragma unroll
    for (int ct = 0; ct < 4; ++ct) cbv[ct] = cb[ct * 16 + col];
    float csum[4] = {0.0f, 0.0f, 0.0f, 0.0f};
#pragma unroll
    for (int lt = 0; lt < 2; ++lt) {
        int l0 = l0base + lt * 16;
        f32x4 acc[4];
#pragma unroll
        for (int ct = 0; ct < 4; ++ct) acc[ct] = (f32x4){0.0f, 0.0f, 0.0f, 0.0f};
#pragma unroll
        for (int tap = 0; tap < 3; ++tap) {
            size_t row = (size_t)b * SEQROW + l0 + col + tap;  // padded: l_in = l + tap - 1
#pragma unroll
            for (int kk = 0; kk < 4; ++kk) {
                short8 av = *(const short8*)(seqb + row * 128 + kk * 32 + kg * 8);
#pragma unroll
                for (int ct = 0; ct < 4; ++ct) {
                    short8 bv = *(const short8*)(wpk + (((tap * 4 + kk) * 4 + ct) << 9) + lane * 8);
                    acc[ct] = __builtin_amdgcn_mfma_f32_16x16x32_bf16(av, bv, acc[ct], 0, 0, 0);
                }
            }
        }
#pragma unroll
        for (int ct = 0; ct < 4; ++ct)
#pragma unroll
            for (int r = 0; r < 4; ++r)
                csum[ct] += fmaxf(acc[ct][r] + cbv[ct], 0.0f);
    }
#pragma unroll
    for (int ct = 0; ct < 4; ++ct) {
        float v = csum[ct];
        v += __shfl_xor(v, 16, 64);
        v += __shfl_xor(v, 32, 64);
        if (lane < 16) atomicAdd(&pooled[b * 64 + ct * 16 + lane], v);
    }
}

// ---------------- head ----------------
__global__ void k_head(const float* __restrict__ pooled, const float* __restrict__ f1w,
                       const float* __restrict__ f1b, const float* __restrict__ f2w,
                       const float* __restrict__ f2b, float* __restrict__ out) {
    int b = blockIdx.x;
    int j = threadIdx.x;
    const float invL = 1.0f / (float)LSEQ;
    float z = f1b[j];
    for (int c = 0; c < 64; ++c)
        z += (pooled[b * 64 + c] * invL) * f1w[c * 64 + j];
    z = fmaxf(z, 0.0f);
    float v = z * f2w[j];
#pragma unroll
    for (int off = 32; off; off >>= 1) v += __shfl_xor(v, off, 64);
    if (j == 0) out[b] = 1.0f / (1.0f + expf(-(v + f2b[0])));
}

extern "C" void kernel_launch(void* const* d_in, const int* in_sizes, int n_in,
                              void* d_out, int out_size, void* d_ws, size_t ws_size,
                              hipStream_t stream) {
    const float* x     = (const float*)d_in[0];
    const int*   ei    = (const int*)d_in[1];
    const int*   depth = (const int*)d_in[2];
    const int*   batch = (const int*)d_in[3];
    const float* W1    = (const float*)d_in[4];
    const float* b1    = (const float*)d_in[5];
    const float* W2    = (const float*)d_in[6];
    const float* b2    = (const float*)d_in[7];
    const float* cw    = (const float*)d_in[8];
    const float* cb    = (const float*)d_in[9];
    const float* f1w   = (const float*)d_in[10];
    const float* f1b   = (const float*)d_in[11];
    const float* f2w   = (const float*)d_in[12];
    const float* f2b   = (const float*)d_in[13];
    float* out = (float*)d_out;

    // ---- workspace layout (~165 MB), each chunk 16B-aligned ----
    char* p = (char*)d_ws;
    auto bump = [&p](size_t bytes) { char* r = p; p += (bytes + 15) & ~(size_t)15; return r; };
    int*      cnt    = (int*)bump((size_t)NN * 4);             // zeroed ┐
    int*      cnt2   = (int*)bump((size_t)NSEG * 4);           //        │ one
    float*    pool   = (float*)bump((size_t)BATCH * 64 * 4);   //        │ k_zero
    ushort_t* seqb   = (ushort_t*)bump((size_t)BATCH * SEQROW * 128 * 2); // ┘ (pad rows stay 0)
    int*      segn   = (int*)bump((size_t)NN * 4);
    int*      nord   = (int*)bump((size_t)NN * 4);
    int*      pos    = (int*)bump((size_t)NN * 4);
    int*      soff   = (int*)bump((size_t)(NSEG + 8) * 4);
    int*      cursor2= (int*)bump((size_t)NSEG * 4);
    float*    dinvs  = (float*)bump((size_t)NN * 4);
    int*      cntp   = (int*)bump((size_t)NN * 4);
    int*      rowoff = (int*)bump((size_t)(NN + 8) * 4);
    int*      cursor = (int*)bump((size_t)NN * 4);
    uint4*    epk    = (uint4*)bump((size_t)NE * 16);
    ushort_t* h1s    = (ushort_t*)bump((size_t)NN * 128);   // reused as aggs after gemm2
    ushort_t* xw2s   = (ushort_t*)bump((size_t)NN * 128);
    ushort_t* W2b    = (ushort_t*)bump((size_t)64 * 64 * 2);
    ushort_t* wpk    = (ushort_t*)bump((size_t)WPKN * 2);
    int*      bsum   = (int*)bump((size_t)512 * 4);
    int*      bsum2  = (int*)bump((size_t)64 * 4);
    ushort_t* aggs   = h1s;  // h1s dead after k_gemm2

    const int* src = ei;
    const int* dst = ei + NE;

    // zero: cnt + cnt2 + pool + seqb (contiguous by layout)
    int zn = NN + NSEG + BATCH * 64 + BATCH * SEQROW * 64 + 16;  // seqb ushorts/2 = words
    k_zero<<<2048, 256, 0, stream>>>((float*)cnt, zn);

    // degree (natural) + seg histograms
    k_hist2<<<(NE + 255) / 256, 256, 0, stream>>>(dst, batch, depth, cnt, segn, cnt2);

    // seg scan -> soff/cursor2 ; node reorder -> nord/pos
    k_scan_block<<<NBLK_S, 256, 0, stream>>>(cnt2, bsum2, NSEG);
    k_scan_top<<<1, 512, 0, stream>>>(bsum2, NBLK_S);
    k_scan_final<<<NBLK_S, 256, 0, stream>>>(cnt2, bsum2, soff, cursor2, NSEG, NN);
    k_nreorder<<<(NN + 255) / 256, 256, 0, stream>>>(segn, cursor2, nord, pos);

    // permute degrees into i-space; dinvs; W2 bf16; conv-weight frag pack
    k_prep<<<(NN + 255) / 256, 256, 0, stream>>>(cnt, nord, dinvs, cntp, W2, W2b, cw, wpk);

    // i-space CSR offsets
    k_scan_block<<<NBLK_E, 256, 0, stream>>>(cntp, bsum, NN);
    k_scan_top<<<1, 512, 0, stream>>>(bsum, NBLK_E);
    k_scan_final<<<NBLK_E, 256, 0, stream>>>(cntp, bsum, rowoff, cursor, NN, NE);

    // edge reorder (single 16B record per edge)
    k_reorder<<<(NE + 255) / 256, 256, 0, stream>>>(src, dst, pos, dinvs, x, cursor, epk);

    // layer-1 build (streaming, bf16 h1s, post-relu)
    k_build1<<<2048, 256, 0, stream>>>(x, W1, b1, dinvs, nord, rowoff, epk, h1s);

    // layer-2 GEMM (MFMA)
    k_gemm2<<<2048, 256, 0, stream>>>(h1s, W2b, xw2s);

    // layer-2 aggregate (flat edge loop, LDS accumulators)
    k_agg3<<<4096, 256, 0, stream>>>(xw2s, b2, dinvs, rowoff, epk, aggs);

    // pool (sequential over seg-sorted rows) -> bf16 padded seq
    k_pool2<<<NSEG / 4, 256, 0, stream>>>(aggs, soff, seqb);

    // conv + bias + relu + L-sum via MFMA
    k_convm<<<256, 256, 0, stream>>>(seqb, wpk, cb, pool);

    // head
    k_head<<<BATCH, 64, 0, stream>>>(pool, f1w, f1b, f2w, f2b, out);
}